// Round 5
// baseline (351.511 us; speedup 1.0000x reference)
//
#include <hip/hip_runtime.h>

#define NPTS  32768
#define DIM   256
#define KCB   1024
#define BM    128      // points per block tile
#define BK    128      // k per block (NSPLIT=8 splits)
#define DT    32
#define NSPLIT 8

#define ZQ_OFF   0
#define LOSS_OFF 8388608
#define IDX_OFF  8388609

// z layout [B, D, H, W]: point n = b*1024 + h*32 + w ; element (n, d) at
// b*262144 + d*1024 + hw
__device__ __forceinline__ int z_base(int n) {
    return ((n >> 10) << 18) | (n & 1023);
}

// ---- numpy pairwise sum (AVX512 npyv order) of squares, 128 elems ----
__device__ __forceinline__ float np_half_sq(const float* __restrict__ p, int stride) {
    float S[16];
#pragma unroll
    for (int l = 0; l < 16; ++l) {
        float t[8];
#pragma unroll
        for (int j = 0; j < 8; ++j) {
            float v = p[(j * 16 + l) * stride];
            t[j] = __fmul_rn(v, v);
        }
        S[l] = __fadd_rn(__fadd_rn(__fadd_rn(t[0], t[1]), __fadd_rn(t[2], t[3])),
                         __fadd_rn(__fadd_rn(t[4], t[5]), __fadd_rn(t[6], t[7])));
    }
    float u[8];
#pragma unroll
    for (int i = 0; i < 8; ++i) u[i] = __fadd_rn(S[i], S[i + 8]);
    float v4[4];
#pragma unroll
    for (int i = 0; i < 4; ++i) v4[i] = __fadd_rn(u[i], u[i + 4]);
    return __fadd_rn(__fadd_rn(v4[0], v4[2]), __fadd_rn(v4[1], v4[3]));
}

__device__ __forceinline__ float np_sum256_sq(const float* __restrict__ p, int stride) {
    return __fadd_rn(np_half_sq(p, stride), np_half_sq(p + 128 * stride, stride));
}

__device__ __forceinline__ unsigned long long pack_vi(float v, int i) {
    unsigned int u = __float_as_uint(v);
    unsigned int key = (u & 0x80000000u) ? ~u : u;   // monotone float->uint (finite)
    return ((unsigned long long)key << 32) | (unsigned int)i;
}

// setup: blocks 0..127 -> z2 + cand init; block 128 -> e2 + zero loss/ticket
__global__ __launch_bounds__(256) void setup_kernel(
    const float* __restrict__ z, const float* __restrict__ emb,
    float* __restrict__ z2, float* __restrict__ e2,
    unsigned long long* __restrict__ cand,
    double* __restrict__ loss_acc, unsigned int* __restrict__ ticket)
{
    if (blockIdx.x < 128) {
        int n = blockIdx.x * 256 + threadIdx.x;
        z2[n] = np_sum256_sq(z + z_base(n), 1024);
        cand[n] = 0x7FFFFFFFFFFFFFFFULL;
    } else {
#pragma unroll
        for (int r = 0; r < 4; ++r) {
            int k = r * 256 + threadIdx.x;
            e2[k] = np_sum256_sq(emb + k * DIM, 1);
        }
        if (threadIdx.x == 0) { *loss_acc = 0.0; *ticket = 0u; }
    }
}

// smem: double-buffered zs [2][32][128] at 0 and 4096; es [2][32][132] at
// 8192 and 8192+4224. Reduction aliases [0..8192) after final barrier.
#define ZS(p)  (smem + (p) * 4096)
#define ES(p)  (smem + 8192 + (p) * 4224)
#define SMEM_FLOATS (8192 + 2 * 4224)

#define FMA_ROW(i, zv)                                      \
    acc[i][0] = __builtin_fmaf(zv, eb0.x, acc[i][0]);       \
    acc[i][1] = __builtin_fmaf(zv, eb0.y, acc[i][1]);       \
    acc[i][2] = __builtin_fmaf(zv, eb0.z, acc[i][2]);       \
    acc[i][3] = __builtin_fmaf(zv, eb0.w, acc[i][3]);       \
    acc[i][4] = __builtin_fmaf(zv, eb1.x, acc[i][4]);       \
    acc[i][5] = __builtin_fmaf(zv, eb1.y, acc[i][5]);       \
    acc[i][6] = __builtin_fmaf(zv, eb1.z, acc[i][6]);       \
    acc[i][7] = __builtin_fmaf(zv, eb1.w, acc[i][7]);

__global__ __launch_bounds__(256) void dist_argmin_kernel(
    const float* __restrict__ z, const float* __restrict__ emb,
    const float* __restrict__ z2w, const float* __restrict__ e2w,
    unsigned long long* __restrict__ cand)
{
    __shared__ __align__(16) float smem[SMEM_FLOATS];

    const int tid = threadIdx.x;
    const int tx = tid & 15;
    const int ty = tid >> 4;
    const int split = blockIdx.x & 7;       // adjacent blocks share pt -> L2 reuse
    const int pt = blockIdx.x >> 3;
    const int n0 = pt << 7;                 // 128 points
    const int k0 = split << 7;              // 128 k

    const int zb = z_base(n0);

    float z2r[8];
#pragma unroll
    for (int i = 0; i < 8; ++i)
        z2r[i] = z2w[n0 + (i >> 2) * 64 + 4 * ty + (i & 3)];

    float bv[8];
    int   bi[8];
#pragma unroll
    for (int i = 0; i < 8; ++i) { bv[i] = __builtin_huge_valf(); bi[i] = 0; }

    // staging thread mapping
    const int sp2 = (tid & 63) * 2;         // point pair for z staging
    const int zd0 = tid >> 6;               // 0..3
    const int edd2 = (tid & 15) * 2;        // d pair for e staging
    const int ekb  = tid >> 4;              // 0..15

    float2 zr[8], er[8];

    // prologue: load + store dt=0 into buffer 0
#pragma unroll
    for (int rr = 0; rr < 8; ++rr)
        zr[rr] = *(const float2*)(z + zb + ((zd0 + 4 * rr) << 10) + sp2);
#pragma unroll
    for (int rr = 0; rr < 8; ++rr)
        er[rr] = *(const float2*)(emb + (k0 + ekb + 16 * rr) * DIM + edd2);
#pragma unroll
    for (int rr = 0; rr < 8; ++rr)
        *(float2*)(ZS(0) + (zd0 + 4 * rr) * 128 + sp2) = zr[rr];
#pragma unroll
    for (int rr = 0; rr < 8; ++rr) {
        float* e0 = ES(0) + edd2 * 132 + ekb + 16 * rr;
        e0[0] = er[rr].x;
        e0[132] = er[rr].y;
    }
    __syncthreads();

    float acc[8][8];
#pragma unroll
    for (int i = 0; i < 8; ++i)
#pragma unroll
        for (int j = 0; j < 8; ++j) acc[i][j] = 0.0f;

#pragma unroll 1
    for (int dt = 0; dt < 8; ++dt) {
        const int p = dt & 1;
        if (dt < 7) {                       // prefetch dt+1 (in flight over compute)
            const int dbase = (dt + 1) * DT;
#pragma unroll
            for (int rr = 0; rr < 8; ++rr)
                zr[rr] = *(const float2*)(z + zb + ((dbase + zd0 + 4 * rr) << 10) + sp2);
#pragma unroll
            for (int rr = 0; rr < 8; ++rr)
                er[rr] = *(const float2*)(emb + (k0 + ekb + 16 * rr) * DIM + dbase + edd2);
        }
        const float* zsp = ZS(p);
        const float* esp = ES(p);
#pragma unroll 2
        for (int dd = 0; dd < DT; ++dd) {
            const float* zrow = zsp + dd * 128;
            const float* erow = esp + dd * 132;
            float4 eb0 = *(const float4*)(erow + 4 * tx);
            float4 eb1 = *(const float4*)(erow + 64 + 4 * tx);
            float4 za0 = *(const float4*)(zrow + 4 * ty);
            float4 za1 = *(const float4*)(zrow + 64 + 4 * ty);
            FMA_ROW(0, za0.x)
            FMA_ROW(1, za0.y)
            FMA_ROW(2, za0.z)
            FMA_ROW(3, za0.w)
            FMA_ROW(4, za1.x)
            FMA_ROW(5, za1.y)
            FMA_ROW(6, za1.z)
            FMA_ROW(7, za1.w)
        }
        if (dt < 7) {                       // store prefetched tile into other buffer
            float* zsn = ZS(p ^ 1);
            float* esn = ES(p ^ 1);
#pragma unroll
            for (int rr = 0; rr < 8; ++rr)
                *(float2*)(zsn + (zd0 + 4 * rr) * 128 + sp2) = zr[rr];
#pragma unroll
            for (int rr = 0; rr < 8; ++rr) {
                float* e0 = esn + edd2 * 132 + ekb + 16 * rr;
                e0[0] = er[rr].x;
                e0[132] = er[rr].y;
            }
            __syncthreads();
        }
    }

    // distances exactly as ref: t1 = z2 + e2 ; d = t1 - 2*dot. k ascending.
#pragma unroll
    for (int j = 0; j < 8; ++j) {
        int k = k0 + (j >> 2) * 64 + 4 * tx + (j & 3);
        float e2v = e2w[k];
#pragma unroll
        for (int i = 0; i < 8; ++i) {
            float t1 = __fadd_rn(z2r[i], e2v);
            float dcur = __fsub_rn(t1, __fmul_rn(2.0f, acc[i][j]));
            if (dcur < bv[i]) { bv[i] = dcur; bi[i] = k; }   // strict <: first min
        }
    }

    // block reduction over tx (16 threads per point row), np tie-break
    __syncthreads();
    float* redv = smem;                     // [128][16]
    int*   redi = (int*)(smem + 2048);      // [128][16]
#pragma unroll
    for (int i = 0; i < 8; ++i) {
        int row = (i >> 2) * 64 + 4 * ty + (i & 3);
        redv[row * 16 + tx] = bv[i];
        redi[row * 16 + tx] = bi[i];
    }
    __syncthreads();
    if (tid < 128) {
        float v = redv[tid * 16];
        int   i = redi[tid * 16];
#pragma unroll
        for (int t = 1; t < 16; ++t) {
            float v2 = redv[tid * 16 + t];
            int   i2 = redi[tid * 16 + t];
            if (v2 < v || (v2 == v && i2 < i)) { v = v2; i = i2; }
        }
        atomicMin(&cand[n0 + tid], pack_vi(v, i));
    }
}

__global__ __launch_bounds__(256) void zq_loss_kernel(
    const float* __restrict__ z, const float* __restrict__ emb,
    const unsigned long long* __restrict__ cand, float* __restrict__ zq,
    float* __restrict__ out_idx, double* __restrict__ loss_acc,
    unsigned int* __restrict__ ticket, float* __restrict__ out_loss)
{
    const int n = blockIdx.x * 256 + threadIdx.x;
    const int kk = (int)(unsigned int)(cand[n] & 0xFFFFFFFFULL);
    out_idx[n] = (float)kk;
    const float* er = emb + kk * DIM;
    const int zb = z_base(n);
    double s = 0.0;
#pragma unroll 8
    for (int d = 0; d < DIM; ++d) {
        float ev = er[d];
        float zv = z[zb + (d << 10)];
        zq[zb + (d << 10)] = ev;
        float df = ev - zv;
        s = fma((double)df, (double)df, s);
    }
    for (int off = 32; off; off >>= 1) s += __shfl_down(s, off, 64);
    __shared__ double sred[4];
    if ((threadIdx.x & 63) == 0) sred[threadIdx.x >> 6] = s;
    __syncthreads();
    if (threadIdx.x == 0) {
        atomicAdd(loss_acc, (sred[0] + sred[1]) + (sred[2] + sred[3]));
        __threadfence();
        unsigned int old = atomicAdd(ticket, 1u);
        if (old == gridDim.x - 1) {
            double total = atomicAdd(loss_acc, 0.0);   // coherent read
            out_loss[0] = (float)(1.25 * (total / 8388608.0));
        }
    }
}

extern "C" void kernel_launch(void* const* d_in, const int* in_sizes, int n_in,
                              void* d_out, int out_size, void* d_ws, size_t ws_size,
                              hipStream_t stream) {
    const float* z   = (const float*)d_in[0];
    const float* emb = (const float*)d_in[1];
    float* out = (float*)d_out;

    // ws: z2[32768] f32 @0 | e2[1024] f32 @131072 | cand[32768] u64 @135168 |
    //     loss f64 @397312 | ticket u32 @397320
    float* z2w = (float*)d_ws;
    float* e2w = (float*)((char*)d_ws + 131072);
    unsigned long long* cand = (unsigned long long*)((char*)d_ws + 135168);
    double* loss_acc = (double*)((char*)d_ws + 397312);
    unsigned int* ticket = (unsigned int*)((char*)d_ws + 397320);

    setup_kernel<<<129, 256, 0, stream>>>(z, emb, z2w, e2w, cand, loss_acc, ticket);
    dist_argmin_kernel<<<(NPTS / BM) * NSPLIT, 256, 0, stream>>>(z, emb, z2w, e2w, cand);
    zq_loss_kernel<<<NPTS / 256, 256, 0, stream>>>(z, emb, cand, out + ZQ_OFF,
                                                   out + IDX_OFF, loss_acc, ticket,
                                                   out + LOSS_OFF);
}

// Round 6
// 250.239 us; speedup vs baseline: 1.4047x; 1.4047x over previous
//
#include <hip/hip_runtime.h>

#define NPTS  32768
#define DIM   256
#define KCB   1024

#define ZQ_OFF   0
#define LOSS_OFF 8388608
#define IDX_OFF  8388609

typedef __attribute__((ext_vector_type(8))) short short8;
typedef __attribute__((ext_vector_type(4))) float f32x4;

// z layout [B, D, H, W]: point n = b*1024 + h*32 + w ; elem (n,d) at b*262144 + d*1024 + hw
__device__ __forceinline__ int z_base(int n) { return ((n >> 10) << 18) | (n & 1023); }

// RNE float->bf16 (bits)
__device__ __forceinline__ unsigned short f2bf(float f) {
    unsigned u = __float_as_uint(f);
    u += 0x7FFFu + ((u >> 16) & 1u);
    return (unsigned short)(u >> 16);
}

__device__ __forceinline__ unsigned long long pack_vi(float v, int i) {
    unsigned int u = __float_as_uint(v);
    unsigned int key = (u & 0x80000000u) ? ~u : u;   // monotone float->uint (finite)
    return ((unsigned long long)key << 32) | (unsigned int)i;
}

// ---- numpy pairwise sum (AVX512 npyv order) of squares, 128 elems ----
__device__ __forceinline__ float np_half_sq(const float* __restrict__ p, int stride) {
    float S[16];
#pragma unroll
    for (int l = 0; l < 16; ++l) {
        float t[8];
#pragma unroll
        for (int j = 0; j < 8; ++j) {
            float v = p[(j * 16 + l) * stride];
            t[j] = __fmul_rn(v, v);
        }
        S[l] = __fadd_rn(__fadd_rn(__fadd_rn(t[0], t[1]), __fadd_rn(t[2], t[3])),
                         __fadd_rn(__fadd_rn(t[4], t[5]), __fadd_rn(t[6], t[7])));
    }
    float u[8];
#pragma unroll
    for (int i = 0; i < 8; ++i) u[i] = __fadd_rn(S[i], S[i + 8]);
    float v4[4];
#pragma unroll
    for (int i = 0; i < 4; ++i) v4[i] = __fadd_rn(u[i], u[i + 4]);
    return __fadd_rn(__fadd_rn(v4[0], v4[2]), __fadd_rn(v4[1], v4[3]));
}
__device__ __forceinline__ float np_sum256_sq(const float* __restrict__ p, int stride) {
    return __fadd_rn(np_half_sq(p, stride), np_half_sq(p + 128 * stride, stride));
}

// blocks 0..127: per-point z2 (np order) + abs-sum -> eps. blocks 128..131: e side.
__global__ __launch_bounds__(256) void setup_kernel(
    const float* __restrict__ z, const float* __restrict__ emb,
    float* __restrict__ z2, float* __restrict__ eps,
    float* __restrict__ e2, float* __restrict__ e2h,
    unsigned short* __restrict__ ebf,
    double* __restrict__ loss_acc, unsigned int* __restrict__ ticket)
{
    if (blockIdx.x < 128) {
        int n = blockIdx.x * 256 + threadIdx.x;
        const float* p = z + z_base(n);
        z2[n] = np_sum256_sq(p, 1024);
        float a = 0.0f;
#pragma unroll 8
        for (int d = 0; d < 256; ++d) a += fabsf(p[d << 10]);
        eps[n] = __builtin_fmaf(1e-5f, a, 3e-4f);   // sound |d~ - d| bound (see derivation)
        if (blockIdx.x == 0 && threadIdx.x == 0) { *loss_acc = 0.0; *ticket = 0u; }
    } else {
        int kb = (blockIdx.x - 128) * 256;
        // coalesced bf16 conversion of 256 emb rows
        for (int idx = threadIdx.x; idx < 256 * 256; idx += 256) {
            int k = kb + (idx >> 8), d = idx & 255;
            ebf[k * 256 + d] = f2bf(emb[k * 256 + d]);
        }
        int k = kb + threadIdx.x;
        float s = np_sum256_sq(emb + k * DIM, 1);
        e2[k] = s;
        e2h[k] = 0.5f * s;
    }
}

// ---------------- MFMA distance + candidate filter + exact recheck ----------------
// block: 64 points x 1024 k. 4 waves, wave tile 32pt x 64k (2 M-tiles x 4 N-tiles).
// zs: bf16 [64pt][264] persistent; es: bf16 [128k][40] double-buffered per 32-d chunk.
#define ZS_STRIDE 264
#define ES_STRIDE 40
#define ES_SIZE   (128 * ES_STRIDE)

__global__ __launch_bounds__(256) void dist_kernel(
    const float* __restrict__ z, const float* __restrict__ emb,
    const unsigned short* __restrict__ ebf,
    const float* __restrict__ z2w, const float* __restrict__ e2w,
    const float* __restrict__ e2hw, const float* __restrict__ epsw,
    float* __restrict__ out_idx)
{
    __shared__ __align__(16) short zs[64 * ZS_STRIDE];
    __shared__ __align__(16) short es[2 * ES_SIZE];
    __shared__ float redbuf[64 * 32];
    __shared__ int   cl[64 * 32];
    __shared__ float MxS[64], thrS[64], epsS[64], z2S[64];
    __shared__ unsigned int cntS[64];
    __shared__ unsigned long long bestS[64];
    __shared__ int ovfS;

    const int tid = threadIdx.x;
    const int w  = tid >> 6;       // wave 0..3
    const int l  = tid & 63;
    const int lq = l >> 4;         // quad 0..3
    const int lr = l & 15;
    const int n0 = blockIdx.x << 6;
    const int zb = z_base(n0);

    if (tid < 64) {
        MxS[tid] = -3.4e38f; thrS[tid] = 3.4e38f;
        cntS[tid] = 0u; bestS[tid] = 0x7FFFFFFFFFFFFFFFULL;
        epsS[tid] = epsw[n0 + tid]; z2S[tid] = z2w[n0 + tid];
    }
    if (tid == 0) ovfS = 0;
    for (int i = tid; i < 64 * 32; i += 256) cl[i] = 0;

    // stage zs (fp32 -> bf16, transpose to [pt][d])
    {
        int q = tid & 15, d0 = tid >> 4;
#pragma unroll 4
        for (int i = 0; i < 16; ++i) {
            int d = d0 + 16 * i;
            float4 v = *(const float4*)(z + zb + (d << 10) + 4 * q);
            zs[(4 * q + 0) * ZS_STRIDE + d] = (short)f2bf(v.x);
            zs[(4 * q + 1) * ZS_STRIDE + d] = (short)f2bf(v.y);
            zs[(4 * q + 2) * ZS_STRIDE + d] = (short)f2bf(v.z);
            zs[(4 * q + 3) * ZS_STRIDE + d] = (short)f2bf(v.w);
        }
    }

    // es staging role: kk = tid>>1, half h = tid&1 (32B of a 64B row-chunk)
    const int skk = tid >> 1, sh = tid & 1;

    // prologue: stage g=0 (kt=0, dt=0)
    {
        const int4* src = (const int4*)(ebf + skk * 256 + sh * 16);
        int4 a = src[0], b = src[1];
        int4* dst = (int4*)(es + skk * ES_STRIDE + sh * 16);
        dst[0] = a; dst[1] = b;
    }
    __syncthreads();

    f32x4 acc[2][4];
#pragma unroll
    for (int mt = 0; mt < 2; ++mt)
#pragma unroll
        for (int nt = 0; nt < 4; ++nt) acc[mt][nt] = (f32x4)0.0f;

    const int mrow = 32 * (w & 1);     // wave's pt-half
    const int kwv  = 64 * (w >> 1);    // wave's k-half within tile

    int4 pa, pb;
#pragma unroll 1
    for (int g = 0; g < 72; ++g) {                 // 9 kt (8 + kt0 redo) x 8 dt
        const int kt = g >> 3, dt = g & 7;
        const int k0 = (kt < 8 ? kt : 0) * 128;
        if (g < 71) {                              // prefetch next chunk
            int gn = g + 1;
            int k0n = ((gn >> 3) < 8 ? (gn >> 3) : 0) * 128;
            const int4* src = (const int4*)(ebf + (k0n + skk) * 256 + (gn & 7) * 32 + sh * 16);
            pa = src[0]; pb = src[1];
        }
        {
            const short* esb = es + (g & 1) * ES_SIZE;
            const int dbase = dt * 32;
            short8 af0 = *(const short8*)(zs + (mrow + lr) * ZS_STRIDE + dbase + lq * 8);
            short8 af1 = *(const short8*)(zs + (mrow + 16 + lr) * ZS_STRIDE + dbase + lq * 8);
#pragma unroll
            for (int nt = 0; nt < 4; ++nt) {
                short8 bf = *(const short8*)(esb + (kwv + 16 * nt + lr) * ES_STRIDE + lq * 8);
                acc[0][nt] = __builtin_amdgcn_mfma_f32_16x16x32_bf16(af0, bf, acc[0][nt], 0, 0, 0);
                acc[1][nt] = __builtin_amdgcn_mfma_f32_16x16x32_bf16(af1, bf, acc[1][nt], 0, 0, 0);
            }
        }
        if (g < 71) {
            int4* dst = (int4*)(es + ((g + 1) & 1) * ES_SIZE + skk * ES_STRIDE + sh * 16);
            dst[0] = pa; dst[1] = pb;
            __syncthreads();
        }
        if (dt == 7) {
            if (g == 71) __syncthreads();
            float e2hr[4]; int kg[4];
#pragma unroll
            for (int nt = 0; nt < 4; ++nt) {
                kg[nt] = k0 + kwv + 16 * nt + lr;
                e2hr[nt] = e2hw[kg[nt]];
            }
            float vals[2][4][4];
#pragma unroll
            for (int mt = 0; mt < 2; ++mt)
#pragma unroll
                for (int nt = 0; nt < 4; ++nt)
#pragma unroll
                    for (int r = 0; r < 4; ++r)
                        vals[mt][nt][r] = acc[mt][nt][r] - e2hr[nt];
            if (kt < 8) {   // merge this kt's max into running Mx, update thr
#pragma unroll
                for (int mt = 0; mt < 2; ++mt)
#pragma unroll
                    for (int r = 0; r < 4; ++r) {
                        float m = fmaxf(fmaxf(vals[mt][0][r], vals[mt][1][r]),
                                        fmaxf(vals[mt][2][r], vals[mt][3][r]));
                        int row = mrow + 16 * mt + lq * 4 + r;
                        redbuf[row * 32 + (w >> 1) * 16 + lr] = m;
                    }
                __syncthreads();
                if (tid < 64) {
                    float m = redbuf[tid * 32];
#pragma unroll 8
                    for (int c = 1; c < 32; ++c) m = fmaxf(m, redbuf[tid * 32 + c]);
                    float Mx = fmaxf(MxS[tid], m);
                    MxS[tid] = Mx;
                    thrS[tid] = Mx - epsS[tid];
                }
                __syncthreads();
            }
            if (kt >= 1) {  // record candidates (kt0 covered by redo at kt==8)
#pragma unroll
                for (int mt = 0; mt < 2; ++mt)
#pragma unroll
                    for (int r = 0; r < 4; ++r) {
                        int row = mrow + 16 * mt + lq * 4 + r;
                        float th = thrS[row];
#pragma unroll
                        for (int nt = 0; nt < 4; ++nt) {
                            if (vals[mt][nt][r] >= th) {
                                unsigned int p = atomicAdd(&cntS[row], 1u);
                                if (p < 32u) cl[row * 32 + p] = kg[nt];
                                else atomicMax(&ovfS, 1);
                            }
                        }
                    }
            }
            if (kt < 8) {
#pragma unroll
                for (int mt = 0; mt < 2; ++mt)
#pragma unroll
                    for (int nt = 0; nt < 4; ++nt) acc[mt][nt] = (f32x4)0.0f;
            }
        }
    }

    // ---------------- exact recheck (bit-identical fp32 chain) ----------------
    __syncthreads();
    float* zx = (float*)es;                 // [32 dd][68] fp32 chunk, reuse es
    const int pt = tid & 63;
    const int s0 = tid >> 6;                // 4 slot-threads per point
    unsigned int nc = cntS[pt]; if (nc > 32u) nc = 32u;
    bool  act[8]; int kE[8]; float accE[8];
#pragma unroll
    for (int j = 0; j < 8; ++j) {
        unsigned int s = (unsigned int)s0 + 4u * j;
        act[j] = s < nc;
        kE[j] = act[j] ? cl[pt * 32 + s] : 0;
        accE[j] = 0.0f;
    }
#pragma unroll 1
    for (int dt = 0; dt < 8; ++dt) {
        const int dbase = dt * 32;
        __syncthreads();
        {
            int q = tid & 15, dd0 = tid >> 4;
            float4 v0 = *(const float4*)(z + zb + ((dbase + dd0) << 10) + 4 * q);
            float4 v1 = *(const float4*)(z + zb + ((dbase + dd0 + 16) << 10) + 4 * q);
            *(float4*)(zx + dd0 * 68 + 4 * q) = v0;
            *(float4*)(zx + (dd0 + 16) * 68 + 4 * q) = v1;
        }
        __syncthreads();
#pragma unroll
        for (int j = 0; j < 8; ++j) {
            if (!act[j]) continue;
            const float* er = emb + kE[j] * 256 + dbase;
            float ev[32];
#pragma unroll
            for (int c = 0; c < 8; ++c) *(float4*)(ev + 4 * c) = *(const float4*)(er + 4 * c);
            float a = accE[j];
#pragma unroll
            for (int dd = 0; dd < 32; ++dd)
                a = __builtin_fmaf(zx[dd * 68 + pt], ev[dd], a);
            accE[j] = a;
        }
    }
#pragma unroll
    for (int j = 0; j < 8; ++j) {
        if (!act[j]) continue;
        int k = kE[j];
        float t1 = __fadd_rn(z2S[pt], e2w[k]);
        float d  = __fsub_rn(t1, __fmul_rn(2.0f, accE[j]));
        atomicMin(&bestS[pt], pack_vi(d, k));
    }
    __syncthreads();

    if (ovfS) {   // near-impossible fallback: full exact scan for overflowed points
        for (int row = 0; row < 64; ++row) {
            if (cntS[row] <= 32u) continue;
            float fa[4] = {0.f, 0.f, 0.f, 0.f};
            for (int dt = 0; dt < 8; ++dt) {
                const int dbase = dt * 32;
                __syncthreads();
                {
                    int q = tid & 15, dd0 = tid >> 4;
                    float4 v0 = *(const float4*)(z + zb + ((dbase + dd0) << 10) + 4 * q);
                    float4 v1 = *(const float4*)(z + zb + ((dbase + dd0 + 16) << 10) + 4 * q);
                    *(float4*)(zx + dd0 * 68 + 4 * q) = v0;
                    *(float4*)(zx + (dd0 + 16) * 68 + 4 * q) = v1;
                }
                __syncthreads();
                for (int c = 0; c < 4; ++c) {
                    const float* er = emb + (tid + 256 * c) * 256 + dbase;
                    for (int dd = 0; dd < 32; ++dd)
                        fa[c] = __builtin_fmaf(zx[dd * 68 + row], er[dd], fa[c]);
                }
            }
            for (int c = 0; c < 4; ++c) {
                int k = tid + 256 * c;
                float t1 = __fadd_rn(z2S[row], e2w[k]);
                float d  = __fsub_rn(t1, __fmul_rn(2.0f, fa[c]));
                atomicMin(&bestS[row], pack_vi(d, k));
            }
            __syncthreads();
        }
    }

    if (tid < 64)
        out_idx[n0 + tid] = (float)(unsigned int)(bestS[tid] & 0xFFFFFFFFULL);
}

__global__ __launch_bounds__(256) void zq_loss_kernel(
    const float* __restrict__ z, const float* __restrict__ emb,
    const float* __restrict__ idxv, float* __restrict__ zq,
    double* __restrict__ loss_acc, unsigned int* __restrict__ ticket,
    float* __restrict__ out_loss)
{
    const int n = blockIdx.x * 256 + threadIdx.x;
    const int kk = (int)idxv[n];
    const float* er = emb + kk * DIM;
    const int zb = z_base(n);
    double s = 0.0;
#pragma unroll 8
    for (int d = 0; d < DIM; ++d) {
        float ev = er[d];
        float zv = z[zb + (d << 10)];
        zq[zb + (d << 10)] = ev;
        float df = ev - zv;
        s = fma((double)df, (double)df, s);
    }
    for (int off = 32; off; off >>= 1) s += __shfl_down(s, off, 64);
    __shared__ double sred[4];
    if ((threadIdx.x & 63) == 0) sred[threadIdx.x >> 6] = s;
    __syncthreads();
    if (threadIdx.x == 0) {
        atomicAdd(loss_acc, (sred[0] + sred[1]) + (sred[2] + sred[3]));
        __threadfence();
        unsigned int old = atomicAdd(ticket, 1u);
        if (old == gridDim.x - 1) {
            double total = atomicAdd(loss_acc, 0.0);
            out_loss[0] = (float)(1.25 * (total / 8388608.0));
        }
    }
}

extern "C" void kernel_launch(void* const* d_in, const int* in_sizes, int n_in,
                              void* d_out, int out_size, void* d_ws, size_t ws_size,
                              hipStream_t stream) {
    const float* z   = (const float*)d_in[0];
    const float* emb = (const float*)d_in[1];
    float* out = (float*)d_out;

    // ws: z2[32768]f32 @0 | eps[32768]f32 @131072 | e2[1024] @262144 |
    //     e2h[1024] @266240 | ebf16[262144]u16 @270336 | loss f64 @794624 | ticket @794632
    float* z2w = (float*)d_ws;
    float* epsw = (float*)((char*)d_ws + 131072);
    float* e2w = (float*)((char*)d_ws + 262144);
    float* e2hw = (float*)((char*)d_ws + 266240);
    unsigned short* ebf = (unsigned short*)((char*)d_ws + 270336);
    double* loss_acc = (double*)((char*)d_ws + 794624);
    unsigned int* ticket = (unsigned int*)((char*)d_ws + 794632);

    setup_kernel<<<132, 256, 0, stream>>>(z, emb, z2w, epsw, e2w, e2hw, ebf,
                                          loss_acc, ticket);
    dist_kernel<<<NPTS / 64, 256, 0, stream>>>(z, emb, ebf, z2w, e2w, e2hw, epsw,
                                               out + IDX_OFF);
    zq_loss_kernel<<<NPTS / 256, 256, 0, stream>>>(z, emb, out + IDX_OFF,
                                                   out + ZQ_OFF, loss_acc, ticket,
                                                   out + LOSS_OFF);
}